// Round 3
// baseline (167.813 us; speedup 1.0000x reference)
//
#include <hip/hip_runtime.h>
#include <math.h>

#define T_LEN 256
#define HID 10

typedef float v2f __attribute__((ext_vector_type(2)));

__device__ __forceinline__ v2f mk2(float a, float b) { v2f r; r.x = a; r.y = b; return r; }
__device__ __forceinline__ v2f splat2(float a) { return mk2(a, a); }

// setup-only accurate softplus
__device__ __forceinline__ float softplus_f(float x) {
    return fmaxf(x, 0.0f) + log1pf(expf(-fabsf(x)));
}
__device__ __forceinline__ float samp(const float* mu, const float* rho,
                                      const float* eps, int i) {
    return mu[i] + softplus_f(rho[i]) * eps[i];
}

// sigmoid = rcp(1 + 2^(-log2e*x))
__device__ __forceinline__ float fast_sigmoid(float x) {
    float e = __builtin_amdgcn_exp2f(-1.442695040888963f * x);
    return __builtin_amdgcn_rcpf(1.0f + e);
}
// tanh(x) = 1 - 2/(2^(2*log2e*x)+1)
__device__ __forceinline__ float fast_tanh(float x) {
    float e = __builtin_amdgcn_exp2f(2.885390081777927f * x);
    return fmaf(-2.0f, __builtin_amdgcn_rcpf(e + 1.0f), 1.0f);
}

__device__ __forceinline__ float bperm_f(int addr, float v) {
    return __int_as_float(__builtin_amdgcn_ds_bpermute(addr, __float_as_int(v)));
}

struct Wreg {
    v2f whh01[HID], whh23[HID];   // recurrent cols {i,f} / {g,o} for this lane's unit
    v2f wih01, wih23, b01, b23;
};

// one LSTM step for one element; h[0..9] are broadcast scalars in registers
__device__ __forceinline__ float lstm_step(const Wreg& w, float xt,
                                           const float h[HID], float& c)
{
    v2f x2 = splat2(xt);
    // even-j chain (seeded with x/bias) and odd-j chain, combined once
    v2f e01 = __builtin_elementwise_fma(x2, w.wih01, w.b01);
    v2f e23 = __builtin_elementwise_fma(x2, w.wih23, w.b23);
    v2f o01 = w.whh01[1] * splat2(h[1]);
    v2f o23 = w.whh23[1] * splat2(h[1]);
    e01 = __builtin_elementwise_fma(splat2(h[0]), w.whh01[0], e01);
    e23 = __builtin_elementwise_fma(splat2(h[0]), w.whh23[0], e23);
    o01 = __builtin_elementwise_fma(splat2(h[3]), w.whh01[3], o01);
    o23 = __builtin_elementwise_fma(splat2(h[3]), w.whh23[3], o23);
    e01 = __builtin_elementwise_fma(splat2(h[2]), w.whh01[2], e01);
    e23 = __builtin_elementwise_fma(splat2(h[2]), w.whh23[2], e23);
    o01 = __builtin_elementwise_fma(splat2(h[5]), w.whh01[5], o01);
    o23 = __builtin_elementwise_fma(splat2(h[5]), w.whh23[5], o23);
    e01 = __builtin_elementwise_fma(splat2(h[4]), w.whh01[4], e01);
    e23 = __builtin_elementwise_fma(splat2(h[4]), w.whh23[4], e23);
    o01 = __builtin_elementwise_fma(splat2(h[7]), w.whh01[7], o01);
    o23 = __builtin_elementwise_fma(splat2(h[7]), w.whh23[7], o23);
    e01 = __builtin_elementwise_fma(splat2(h[6]), w.whh01[6], e01);
    e23 = __builtin_elementwise_fma(splat2(h[6]), w.whh23[6], e23);
    o01 = __builtin_elementwise_fma(splat2(h[9]), w.whh01[9], o01);
    o23 = __builtin_elementwise_fma(splat2(h[9]), w.whh23[9], o23);
    e01 = __builtin_elementwise_fma(splat2(h[8]), w.whh01[8], e01);
    e23 = __builtin_elementwise_fma(splat2(h[8]), w.whh23[8], e23);
    v2f a01 = e01 + o01;
    v2f a23 = e23 + o23;
    float ig = fast_sigmoid(a01.x);
    float fg = fast_sigmoid(a01.y);
    float gg = fast_tanh(a23.x);
    float og = fast_sigmoid(a23.y);
    c = fmaf(fg, c, ig * gg);
    return og * fast_tanh(c);
}

// One wave per block; 4 elements per wave (one per 10-lane group; lanes 40..63
// ride along on dummy groups). 8192/4 = 2048 blocks = exactly 2 waves/SIMD,
// perfectly balanced. NO __shared__: h is exchanged with ds_bpermute (one DS
// hop, no write->read round trip, no ordering drain against an LDS buffer).
__global__ __launch_bounds__(64) void bayes_lstm_kernel(
    const float* __restrict__ x,
    const float* __restrict__ w_ih_mu, const float* __restrict__ w_ih_rho,
    const float* __restrict__ w_hh_mu, const float* __restrict__ w_hh_rho,
    const float* __restrict__ b_mu,    const float* __restrict__ b_rho,
    const float* __restrict__ eps_ih,  const float* __restrict__ eps_hh,
    const float* __restrict__ eps_b,
    const float* __restrict__ lin_w,   const float* __restrict__ lin_b,
    float* __restrict__ out, int n_elem)
{
    const int lane  = threadIdx.x;       // 0..63
    const int g     = lane / 10;         // 0..6 (groups >=4 are dummies)
    const int k     = lane - g * 10;     // 0..9 (unit index)
    const bool valid = (g < 4);
    const int gbase = valid ? g * 10 : 0;  // dummy groups alias group 0 (in-range)
    const int b     = blockIdx.x * 4 + g;
    const int b_eff = (valid && b < n_elem) ? b : 0;   // clamp for safe loads

    // ---- sample weights into registers (k < 10 for every lane) ----
    Wreg w;
    const int c0 = k, c1 = HID + k, c2 = 2 * HID + k, c3 = 3 * HID + k;
    w.wih01 = mk2(samp(w_ih_mu, w_ih_rho, eps_ih, c0), samp(w_ih_mu, w_ih_rho, eps_ih, c1));
    w.wih23 = mk2(samp(w_ih_mu, w_ih_rho, eps_ih, c2), samp(w_ih_mu, w_ih_rho, eps_ih, c3));
    w.b01   = mk2(samp(b_mu, b_rho, eps_b, c0), samp(b_mu, b_rho, eps_b, c1));
    w.b23   = mk2(samp(b_mu, b_rho, eps_b, c2), samp(b_mu, b_rho, eps_b, c3));
#pragma unroll
    for (int j = 0; j < HID; ++j) {
        w.whh01[j] = mk2(samp(w_hh_mu, w_hh_rho, eps_hh, j * 4 * HID + c0),
                         samp(w_hh_mu, w_hh_rho, eps_hh, j * 4 * HID + c1));
        w.whh23[j] = mk2(samp(w_hh_mu, w_hh_rho, eps_hh, j * 4 * HID + c2),
                         samp(w_hh_mu, w_hh_rho, eps_hh, j * 4 * HID + c3));
    }

    // loop-invariant bpermute lane addresses (byte = lane*4)
    int ha[HID];
#pragma unroll
    for (int j = 0; j < HID; ++j) ha[j] = (gbase + j) * 4;
    int xa[8];
#pragma unroll
    for (int t = 0; t < 8; ++t) xa[t] = (gbase + t) * 4;

    float c = 0.f, hk = 0.f;
    const float* xr = x + (size_t)b_eff * T_LEN;
    const bool ldx = (k < 8);
    float xc = ldx ? xr[k] : 0.f;        // chunk 0: lane gbase+k holds x[t=k]

    for (int ch = 0; ch < 32; ++ch) {    // 32 chunks x 8 steps = 256
        float xn = 0.f;
        if (ldx && ch < 31) xn = xr[(ch + 1) * 8 + k];   // prefetch next chunk
        // broadcast this chunk's 8 x values up front (independent of h chain)
        float xt[8];
#pragma unroll
        for (int t = 0; t < 8; ++t) xt[t] = bperm_f(xa[t], xc);
#pragma unroll
        for (int ti = 0; ti < 8; ++ti) {
            // gather h[t-1] from the 10 lanes of this group (10 independent
            // bpermutes; counted lgkmcnt lets the FMA chain start early)
            float h[HID];
#pragma unroll
            for (int j = 0; j < HID; ++j) h[j] = bperm_f(ha[j], hk);
            hk = lstm_step(w, xt[ti], h, c);
        }
        xc = xn;
    }

    // ---- linear head: broadcast final h, every lane computes the full dot ----
    float hf[HID];
#pragma unroll
    for (int j = 0; j < HID; ++j) hf[j] = bperm_f(ha[j], hk);
    if (k == 0 && valid && b < n_elem) {
        float acc = lin_b[0];
#pragma unroll
        for (int j = 0; j < HID; ++j) acc = fmaf(lin_w[j], hf[j], acc);
        out[b] = acc;
    }
}

extern "C" void kernel_launch(void* const* d_in, const int* in_sizes, int n_in,
                              void* d_out, int out_size, void* d_ws, size_t ws_size,
                              hipStream_t stream) {
    const float* x        = (const float*)d_in[0];
    const float* w_ih_mu  = (const float*)d_in[1];
    const float* w_ih_rho = (const float*)d_in[2];
    const float* w_hh_mu  = (const float*)d_in[3];
    const float* w_hh_rho = (const float*)d_in[4];
    const float* b_mu     = (const float*)d_in[5];
    const float* b_rho    = (const float*)d_in[6];
    const float* eps_ih   = (const float*)d_in[7];
    const float* eps_hh   = (const float*)d_in[8];
    const float* eps_b    = (const float*)d_in[9];
    const float* lin_w    = (const float*)d_in[10];
    const float* lin_b    = (const float*)d_in[11];
    float* out = (float*)d_out;

    const int n_b = in_sizes[0] / T_LEN;     // 8192
    dim3 grid((n_b + 3) / 4), block(64);     // 1 wave/block, 4 elements/wave
    hipLaunchKernelGGL(bayes_lstm_kernel, grid, block, 0, stream,
                       x, w_ih_mu, w_ih_rho, w_hh_mu, w_hh_rho, b_mu, b_rho,
                       eps_ih, eps_hh, eps_b, lin_w, lin_b, out, n_b);
}